// Round 17
// baseline (146.914 us; speedup 1.0000x reference)
//
#include <hip/hip_runtime.h>
#include <hip/hip_fp16.h>
#include <hip/hip_cooperative_groups.h>

namespace cg = cooperative_groups;

// out[m][n] = fp16( fp16( (sum_k x[m][k]*w6[n][k]) * scale[n] ) + bias[n] ), stored fp32
// v17: single cooperative dispatch fusing xcvt -> gemm(v15 body, unchanged) -> finalize.
// Removes 2 kernel-launch overheads + inter-kernel gaps (r16: gemm improved ~2x but
// total barely moved -> pipeline tax, not gemm, now dominates). Fallback: v15 3-kernel.

typedef __attribute__((ext_vector_type(8))) _Float16 half8;
typedef __attribute__((ext_vector_type(2))) __fp16 fp16x2;   // cvt_pkrtz return type
typedef __attribute__((ext_vector_type(4))) float f32x4;

typedef const __attribute__((address_space(1))) void* gptr_t;
typedef __attribute__((address_space(3))) void* lptr_t;

constexpr int K = 4096, N = 4096, M = 256;
constexpr int BM = 128, BN = 128, BK = 32;
constexpr int SPL = 8;
constexpr int KSPL = K / SPL;     // 512
constexpr int NT = KSPL / BK;     // 16 phases

__device__ __forceinline__ void gload16(const void* g, void* l) {
    __builtin_amdgcn_global_load_lds((gptr_t)g, (lptr_t)l, 16, 0, 0);
}

__device__ __forceinline__ half8 cvt8(float4 f0, float4 f1) {   // exact: fp16-exact data
    fp16x2 p0 = __builtin_amdgcn_cvt_pkrtz(f0.x, f0.y);
    fp16x2 p1 = __builtin_amdgcn_cvt_pkrtz(f0.z, f0.w);
    fp16x2 p2 = __builtin_amdgcn_cvt_pkrtz(f1.x, f1.y);
    fp16x2 p3 = __builtin_amdgcn_cvt_pkrtz(f1.z, f1.w);
    half8 h;
    h[0]=(_Float16)p0[0]; h[1]=(_Float16)p0[1];
    h[2]=(_Float16)p1[0]; h[3]=(_Float16)p1[1];
    h[4]=(_Float16)p2[0]; h[5]=(_Float16)p2[1];
    h[6]=(_Float16)p3[0]; h[7]=(_Float16)p3[1];
    return h;
}

// ---- v15 gemm body, verbatim (blockIdx.x-based), callable from fused + standalone ----
__device__ __forceinline__ void gemm_body(const _Float16* __restrict__ X16,
                                          const float* __restrict__ W,
                                          float* __restrict__ P)
{
    __shared__ __align__(16) _Float16 LA[2][BM * BK];   // 2 x 8 KB
    __shared__ __align__(16) float    LB[2][BN * BK];   // 2 x 16 KB

    const int tid = (int)threadIdx.x;
    const int l   = tid & 63;
    const int wv  = tid >> 6;           // 4 waves: 2(M) x 2(N), wave tile 64x64
    const int lc  = l & 15;
    const int lr  = l >> 4;
    const int wm  = (wv & 1) * 64;
    const int wn  = (wv >> 1) * 64;

    const int bid = (int)blockIdx.x;
    const int xcd = bid & 7;
    const int i   = bid >> 3;           // 0..63
    const int mb  = i & 1;
    const int sp  = (i >> 1) & 7;
    const int nbl = i >> 4;             // 0..3
    const int bm  = mb * BM;
    const int bn  = (xcd * 4 + nbl) * BN;
    const int kb  = sp * KSPL;

    // DMA staging maps (LDS linear dest, global source pre-XOR-swizzled)
    const int arow = wv * 32 + (l >> 2);
    const int acho = ((l & 3) ^ ((l >> 3) & 3)) * 8;
    const _Float16* ag0 = X16 + (size_t)(bm + arow)      * K + kb + acho;
    const _Float16* ag1 = X16 + (size_t)(bm + arow + 16) * K + kb + acho;
    const int asl0 = (wv * 32) * BK;
    const int asl1 = (wv * 32 + 16) * BK;
    const int wrow = wv * 32 + (l >> 3);
    const int wcho = ((l & 7) ^ (l >> 3)) * 4;
    const float* wg0 = W + (size_t)(bn + wrow)      * K + kb + wcho;
    const float* wg1 = W + (size_t)(bn + wrow + 8)  * K + kb + wcho;
    const float* wg2 = W + (size_t)(bn + wrow + 16) * K + kb + wcho;
    const float* wg3 = W + (size_t)(bn + wrow + 24) * K + kb + wcho;
    const int wsl0 = (wv * 32 + 0)  * BK;
    const int wsl1 = (wv * 32 + 8)  * BK;
    const int wsl2 = (wv * 32 + 16) * BK;
    const int wsl3 = (wv * 32 + 24) * BK;

#define STAGE(t, bf) do {                                               \
        gload16(ag0 + (size_t)(t) * BK, &LA[bf][asl0]);                 \
        gload16(ag1 + (size_t)(t) * BK, &LA[bf][asl1]);                 \
        gload16(wg0 + (size_t)(t) * BK, &LB[bf][wsl0]);                 \
        gload16(wg1 + (size_t)(t) * BK, &LB[bf][wsl1]);                 \
        gload16(wg2 + (size_t)(t) * BK, &LB[bf][wsl2]);                 \
        gload16(wg3 + (size_t)(t) * BK, &LB[bf][wsl3]);                 \
    } while (0)

    // frag read offsets (swizzled; conflict-free, r15-verified)
    const int aswz = (lr ^ ((lc >> 1) & 3)) << 3;
    const int wsz0 = (((lr << 1))     ^ (lc & 7)) << 2;
    const int wsz1 = (((lr << 1) | 1) ^ (lc & 7)) << 2;

    f32x4 acc[4][4];
    #pragma unroll
    for (int a = 0; a < 4; ++a)
        #pragma unroll
        for (int b = 0; b < 4; ++b)
            acc[a][b] = (f32x4){0.f, 0.f, 0.f, 0.f};

#define COMPUTE(bf) do {                                                \
        half8 af[4];                                                    \
        _Pragma("unroll")                                               \
        for (int ar = 0; ar < 4; ++ar)                                  \
            af[ar] = *(const half8*)(&LA[bf][(wm + ar * 16 + lc) * BK + aswz]); \
        _Pragma("unroll")                                               \
        for (int br = 0; br < 4; ++br) {                                \
            const float* pw = &LB[bf][(wn + br * 16 + lc) * BK];        \
            float4 b0 = *(const float4*)(pw + wsz0);                    \
            float4 b1 = *(const float4*)(pw + wsz1);                    \
            half8 bb = cvt8(b0, b1);                                    \
            acc[0][br] = __builtin_amdgcn_mfma_f32_16x16x32_f16(af[0], bb, acc[0][br], 0, 0, 0); \
            acc[1][br] = __builtin_amdgcn_mfma_f32_16x16x32_f16(af[1], bb, acc[1][br], 0, 0, 0); \
            acc[2][br] = __builtin_amdgcn_mfma_f32_16x16x32_f16(af[2], bb, acc[2][br], 0, 0, 0); \
            acc[3][br] = __builtin_amdgcn_mfma_f32_16x16x32_f16(af[3], bb, acc[3][br], 0, 0, 0); \
        } } while (0)

    STAGE(0, 0);
    for (int t = 0; t < NT; ++t) {
        if (t + 1 < NT) {
            STAGE(t + 1, (t + 1) & 1);
            asm volatile("s_waitcnt vmcnt(6)" ::: "memory");
        } else {
            asm volatile("s_waitcnt vmcnt(0)" ::: "memory");
        }
        __builtin_amdgcn_sched_barrier(0);
        __builtin_amdgcn_s_barrier();
        __builtin_amdgcn_sched_barrier(0);
        COMPUTE(t & 1);
        __builtin_amdgcn_sched_barrier(0);
        __builtin_amdgcn_s_barrier();
    }
#undef STAGE
#undef COMPUTE

    float* Pb = P + (size_t)sp * M * N;
    const int orow = bm + wm + lr * 4;
    const int ocol = bn + wn + lc;
    #pragma unroll
    for (int ar = 0; ar < 4; ++ar)
        #pragma unroll
        for (int br = 0; br < 4; ++br)
            #pragma unroll
            for (int r = 0; r < 4; ++r)
                Pb[(size_t)(orow + ar * 16 + r) * N + ocol + br * 16] = acc[ar][br][r];
}

// ---- fused cooperative kernel: xcvt -> gemm -> finalize, one dispatch ----
__global__ __launch_bounds__(256, 3)
void fused(const float* __restrict__ X, const float* __restrict__ W,
           const float* __restrict__ S, const float* __restrict__ Bi,
           float* __restrict__ O, _Float16* __restrict__ X16,
           float* __restrict__ P)
{
    // phase 0: X fp32 -> fp16 (exact); 512 blk x 256 thr x 8 = M*K exactly
    {
        const int i = ((int)blockIdx.x * 256 + (int)threadIdx.x) * 8;
        float4 a = *(const float4*)(X + i);
        float4 b = *(const float4*)(X + i + 4);
        *(half8*)(X16 + i) = cvt8(a, b);
    }
    cg::this_grid().sync();
    gemm_body(X16, W, P);
    cg::this_grid().sync();
    // phase 2: finalize; 512 blk x 256 thr x 2 float4 = M*N exactly
    {
        const int gt = (int)blockIdx.x * 256 + (int)threadIdx.x;
        #pragma unroll
        for (int rep = 0; rep < 2; ++rep) {
            const size_t i = ((size_t)(gt * 2 + rep)) * 4;
            const int n = (int)(i & (N - 1));
            float4 v = *(const float4*)(P + i);
            #pragma unroll
            for (int s = 1; s < SPL; ++s) {
                float4 u = *(const float4*)(P + (size_t)s * M * N + i);
                v.x += u.x; v.y += u.y; v.z += u.z; v.w += u.w;
            }
            float4 sc = *(const float4*)(S + n);
            float4 bb = *(const float4*)(Bi + n);
            v.x = (float)(_Float16)((float)(_Float16)(v.x * sc.x) + bb.x);
            v.y = (float)(_Float16)((float)(_Float16)(v.y * sc.y) + bb.y);
            v.z = (float)(_Float16)((float)(_Float16)(v.z * sc.z) + bb.z);
            v.w = (float)(_Float16)((float)(_Float16)(v.w * sc.w) + bb.w);
            *(float4*)(O + i) = v;
        }
    }
}

// ---- fallback path (v15 3-kernel) ----
__global__ __launch_bounds__(256)
void xcvt(const float* __restrict__ X, _Float16* __restrict__ X16)
{
    const int i = ((int)blockIdx.x * 256 + (int)threadIdx.x) * 8;
    float4 a = *(const float4*)(X + i);
    float4 b = *(const float4*)(X + i + 4);
    *(half8*)(X16 + i) = cvt8(a, b);
}

__global__ __launch_bounds__(256, 3)
void gemm_k(const _Float16* __restrict__ X16, const float* __restrict__ W,
            float* __restrict__ P)
{
    gemm_body(X16, W, P);
}

__global__ __launch_bounds__(256)
void finalize(const float* __restrict__ P, const float* __restrict__ S,
              const float* __restrict__ Bi, float* __restrict__ O)
{
    const size_t i = ((size_t)blockIdx.x * 256 + threadIdx.x) * 4;
    const int n = (int)(i & (N - 1));
    float4 v = *(const float4*)(P + i);
    #pragma unroll
    for (int s = 1; s < SPL; ++s) {
        float4 u = *(const float4*)(P + (size_t)s * M * N + i);
        v.x += u.x; v.y += u.y; v.z += u.z; v.w += u.w;
    }
    float4 sc = *(const float4*)(S + n);
    float4 bb = *(const float4*)(Bi + n);
    v.x = (float)(_Float16)((float)(_Float16)(v.x * sc.x) + bb.x);
    v.y = (float)(_Float16)((float)(_Float16)(v.y * sc.y) + bb.y);
    v.z = (float)(_Float16)((float)(_Float16)(v.z * sc.z) + bb.z);
    v.w = (float)(_Float16)((float)(_Float16)(v.w * sc.w) + bb.w);
    *(float4*)(O + i) = v;
}

// correctness fallback if d_ws is too small
__global__ __launch_bounds__(256)
void fp6lin_small(const float* __restrict__ X, const float* __restrict__ W,
                  const float* __restrict__ S, const float* __restrict__ Bi,
                  float* __restrict__ O)
{
    const int n = (int)blockIdx.x;
    const int m = (int)threadIdx.x;
    float s = 0.f;
    for (int k = 0; k < K; ++k)
        s += (float)(_Float16)X[(size_t)m * K + k] * (float)(_Float16)W[(size_t)n * K + k];
    O[(size_t)m * N + n] = (float)(_Float16)((float)(_Float16)(s * S[n]) + Bi[n]);
}

extern "C" void kernel_launch(void* const* d_in, const int* in_sizes, int n_in,
                              void* d_out, int out_size, void* d_ws, size_t ws_size,
                              hipStream_t stream) {
    const float* x  = (const float*)d_in[0];
    const float* w  = (const float*)d_in[1];
    const float* s  = (const float*)d_in[2];
    const float* bi = (const float*)d_in[3];
    float* o = (float*)d_out;

    const size_t xbytes = (size_t)M * K * 2;              // 2 MB fp16 X
    const size_t slice  = (size_t)M * N * sizeof(float);  // 4 MB per partial
    _Float16* x16 = (_Float16*)d_ws;
    float*    P   = (float*)((char*)d_ws + xbytes);

    if (ws_size >= xbytes + SPL * slice) {
        void* args[] = { (void*)&x, (void*)&w, (void*)&s, (void*)&bi,
                         (void*)&o, (void*)&x16, (void*)&P };
        hipError_t e = hipLaunchCooperativeKernel((const void*)fused,
                                                  dim3(512), dim3(256),
                                                  args, 0, stream);
        if (e != hipSuccess) {
            // fallback: 3-kernel v15 path
            xcvt<<<dim3(M * K / 8 / 256), dim3(256), 0, stream>>>(x, x16);
            gemm_k<<<dim3(512), dim3(256), 0, stream>>>(x16, w, P);
            finalize<<<dim3(M * N / 4 / 256), dim3(256), 0, stream>>>(P, s, bi, o);
        }
    } else {
        fp6lin_small<<<dim3(N), dim3(M), 0, stream>>>(x, w, s, bi, o);
    }
}

// Round 19
// 31.523 us; speedup vs baseline: 4.6606x; 4.6606x over previous
//
#include <hip/hip_runtime.h>
#include <hip/hip_fp16.h>

// out[m][n] = fp16( fp16( (sum_k x[m][k]*w6[n][k]) * scale[n] ) + bias[n] ), stored fp32
// v18: 2-kernel path. gemm = v15 schedule (128x128, 4 waves, wave-tile 64x64, BK=32,
// double-buffered DMA staging, counted vmcnt, raw barriers, XOR swizzle) but X staged
// DIRECTLY as fp32 (drops the xcvt kernel; A frags cvt in-path like W). Partials
// stored fp16 (range: |partial| <~ 800 << 65504; induced error ~3e-4 << 0.131 thr)
// -> finalize traffic halved. SPL=8.

typedef __attribute__((ext_vector_type(8))) _Float16 half8;
typedef __attribute__((ext_vector_type(2))) __fp16 fp16x2;   // cvt_pkrtz return type
typedef __attribute__((ext_vector_type(4))) float f32x4;

typedef const __attribute__((address_space(1))) void* gptr_t;
typedef __attribute__((address_space(3))) void* lptr_t;

constexpr int K = 4096, N = 4096, M = 256;
constexpr int BM = 128, BN = 128, BK = 32;
constexpr int SPL = 8;
constexpr int KSPL = K / SPL;     // 512
constexpr int NT = KSPL / BK;     // 16 phases

__device__ __forceinline__ void gload16(const void* g, void* l) {
    __builtin_amdgcn_global_load_lds((gptr_t)g, (lptr_t)l, 16, 0, 0);
}

__device__ __forceinline__ half8 cvt8(float4 f0, float4 f1) {   // exact: fp16-exact data
    fp16x2 p0 = __builtin_amdgcn_cvt_pkrtz(f0.x, f0.y);
    fp16x2 p1 = __builtin_amdgcn_cvt_pkrtz(f0.z, f0.w);
    fp16x2 p2 = __builtin_amdgcn_cvt_pkrtz(f1.x, f1.y);
    fp16x2 p3 = __builtin_amdgcn_cvt_pkrtz(f1.z, f1.w);
    half8 h;
    h[0]=(_Float16)p0[0]; h[1]=(_Float16)p0[1];
    h[2]=(_Float16)p1[0]; h[3]=(_Float16)p1[1];
    h[4]=(_Float16)p2[0]; h[5]=(_Float16)p2[1];
    h[6]=(_Float16)p3[0]; h[7]=(_Float16)p3[1];
    return h;
}

__global__ __launch_bounds__(256, 2)
void gemm(const float* __restrict__ X,
          const float* __restrict__ W,
          _Float16* __restrict__ P)     // [SPL][M][N] fp16 partials
{
    __shared__ __align__(16) float LA[2][BM * BK];   // 2 x 16 KB (X fp32)
    __shared__ __align__(16) float LB[2][BN * BK];   // 2 x 16 KB (W fp32)

    const int tid = (int)threadIdx.x;
    const int l   = tid & 63;
    const int wv  = tid >> 6;           // 4 waves: 2(M) x 2(N), wave tile 64x64
    const int lc  = l & 15;
    const int lr  = l >> 4;
    const int wm  = (wv & 1) * 64;
    const int wn  = (wv >> 1) * 64;

    // XCD map: per XCD 4 N-tiles (512 W rows, HBM-read once); mb fastest so the
    // 2 blocks sharing a W k-slab are co-resident+co-timed on one XCD.
    const int bid = (int)blockIdx.x;
    const int xcd = bid & 7;
    const int i   = bid >> 3;           // 0..63
    const int mb  = i & 1;
    const int sp  = (i >> 1) & 7;
    const int nbl = i >> 4;             // 0..3
    const int bm  = mb * BM;
    const int bn  = (xcd * 4 + nbl) * BN;
    const int kb  = sp * KSPL;

    // ---- DMA staging (identical geometry for A and W: 16 KB = 16 insts of 1KB,
    //      1KB = 8 rows x 128B; wave wv does 4 insts; lane l -> row l>>3, chunk l&7;
    //      global source chunk pre-swizzled: (l&7) ^ (l>>3) since row&7 == l>>3) ----
    const int srow = wv * 32 + (l >> 3);             // +8 per inst
    const int scho = ((l & 7) ^ (l >> 3)) * 4;       // floats
    const float* ag0 = X + (size_t)(bm + srow)      * K + kb + scho;
    const float* ag1 = X + (size_t)(bm + srow + 8)  * K + kb + scho;
    const float* ag2 = X + (size_t)(bm + srow + 16) * K + kb + scho;
    const float* ag3 = X + (size_t)(bm + srow + 24) * K + kb + scho;
    const float* wg0 = W + (size_t)(bn + srow)      * K + kb + scho;
    const float* wg1 = W + (size_t)(bn + srow + 8)  * K + kb + scho;
    const float* wg2 = W + (size_t)(bn + srow + 16) * K + kb + scho;
    const float* wg3 = W + (size_t)(bn + srow + 24) * K + kb + scho;
    const int sl0 = (wv * 32 + 0)  * BK;             // LDS float-index of inst slabs
    const int sl1 = (wv * 32 + 8)  * BK;
    const int sl2 = (wv * 32 + 16) * BK;
    const int sl3 = (wv * 32 + 24) * BK;

#define STAGE(t, bf) do {                                               \
        gload16(ag0 + (size_t)(t) * BK, &LA[bf][sl0]);                  \
        gload16(ag1 + (size_t)(t) * BK, &LA[bf][sl1]);                  \
        gload16(ag2 + (size_t)(t) * BK, &LA[bf][sl2]);                  \
        gload16(ag3 + (size_t)(t) * BK, &LA[bf][sl3]);                  \
        gload16(wg0 + (size_t)(t) * BK, &LB[bf][sl0]);                  \
        gload16(wg1 + (size_t)(t) * BK, &LB[bf][sl1]);                  \
        gload16(wg2 + (size_t)(t) * BK, &LB[bf][sl2]);                  \
        gload16(wg3 + (size_t)(t) * BK, &LB[bf][sl3]);                  \
    } while (0)   // exactly 8 vmem ops per wave per tile

    // ---- frag read offsets (row = base+16q+lc -> row&7 == lc&7; fp32 chunk pair
    //      {2lr, 2lr+1} stored XOR (lc&7)) ----
    const int sz0 = (((lr << 1))     ^ (lc & 7)) << 2;   // floats
    const int sz1 = (((lr << 1) | 1) ^ (lc & 7)) << 2;

    f32x4 acc[4][4];
    #pragma unroll
    for (int a = 0; a < 4; ++a)
        #pragma unroll
        for (int b = 0; b < 4; ++b)
            acc[a][b] = (f32x4){0.f, 0.f, 0.f, 0.f};

#define COMPUTE(bf) do {                                                \
        half8 af[4];                                                    \
        _Pragma("unroll")                                               \
        for (int ar = 0; ar < 4; ++ar) {                                \
            const float* pa = &LA[bf][(wm + ar * 16 + lc) * BK];        \
            af[ar] = cvt8(*(const float4*)(pa + sz0),                   \
                          *(const float4*)(pa + sz1));                  \
        }                                                               \
        _Pragma("unroll")                                               \
        for (int br = 0; br < 4; ++br) {                                \
            const float* pw = &LB[bf][(wn + br * 16 + lc) * BK];        \
            half8 bb = cvt8(*(const float4*)(pw + sz0),                 \
                            *(const float4*)(pw + sz1));                \
            acc[0][br] = __builtin_amdgcn_mfma_f32_16x16x32_f16(af[0], bb, acc[0][br], 0, 0, 0); \
            acc[1][br] = __builtin_amdgcn_mfma_f32_16x16x32_f16(af[1], bb, acc[1][br], 0, 0, 0); \
            acc[2][br] = __builtin_amdgcn_mfma_f32_16x16x32_f16(af[2], bb, acc[2][br], 0, 0, 0); \
            acc[3][br] = __builtin_amdgcn_mfma_f32_16x16x32_f16(af[3], bb, acc[3][br], 0, 0, 0); \
        } } while (0)

    // prologue: prime tile 0
    STAGE(0, 0);

    for (int t = 0; t < NT; ++t) {
        if (t + 1 < NT) {
            STAGE(t + 1, (t + 1) & 1);           // issue BEFORE compute (T3)
            asm volatile("s_waitcnt vmcnt(8)" ::: "memory");  // tile t landed
        } else {
            asm volatile("s_waitcnt vmcnt(0)" ::: "memory");
        }
        __builtin_amdgcn_sched_barrier(0);
        __builtin_amdgcn_s_barrier();            // raw barrier: no vmcnt(0) drain
        __builtin_amdgcn_sched_barrier(0);
        COMPUTE(t & 1);
        __builtin_amdgcn_sched_barrier(0);
        __builtin_amdgcn_s_barrier();            // readers done before re-stage
    }
#undef STAGE
#undef COMPUTE

    // fp16 partial stores. C/D: col = lane&15, row = (lane>>4)*4 + reg [m89/m91]
    _Float16* Pb = P + (size_t)sp * M * N;
    const int orow = bm + wm + lr * 4;
    const int ocol = bn + wn + lc;
    #pragma unroll
    for (int ar = 0; ar < 4; ++ar)
        #pragma unroll
        for (int br = 0; br < 4; ++br)
            #pragma unroll
            for (int r = 0; r < 4; ++r)
                Pb[(size_t)(orow + ar * 16 + r) * N + ocol + br * 16]
                    = (_Float16)acc[ar][br][r];
}

// O = fp32( fp16( fp16( (sum of SPL fp16 partials) * scale[n] ) + bias[n] ) )
__global__ __launch_bounds__(256)
void finalize(const _Float16* __restrict__ P,
              const float* __restrict__ S,
              const float* __restrict__ Bi,
              float* __restrict__ O)
{
    const size_t i = ((size_t)blockIdx.x * 256 + threadIdx.x) * 8;
    const int n = (int)(i & (N - 1));
    float acc[8] = {0.f, 0.f, 0.f, 0.f, 0.f, 0.f, 0.f, 0.f};
    #pragma unroll
    for (int s = 0; s < SPL; ++s) {
        half8 u = *(const half8*)(P + (size_t)s * M * N + i);
        #pragma unroll
        for (int e = 0; e < 8; ++e) acc[e] += (float)u[e];
    }
    float4 sc0 = *(const float4*)(S + n);
    float4 sc1 = *(const float4*)(S + n + 4);
    float4 bb0 = *(const float4*)(Bi + n);
    float4 bb1 = *(const float4*)(Bi + n + 4);
    float sc[8] = {sc0.x, sc0.y, sc0.z, sc0.w, sc1.x, sc1.y, sc1.z, sc1.w};
    float bb[8] = {bb0.x, bb0.y, bb0.z, bb0.w, bb1.x, bb1.y, bb1.z, bb1.w};
    float out[8];
    #pragma unroll
    for (int e = 0; e < 8; ++e)
        out[e] = (float)(_Float16)((float)(_Float16)(acc[e] * sc[e]) + bb[e]);
    *(float4*)(O + i)     = (float4){out[0], out[1], out[2], out[3]};
    *(float4*)(O + i + 4) = (float4){out[4], out[5], out[6], out[7]};
}

// correctness fallback if d_ws is too small
__global__ __launch_bounds__(256)
void fp6lin_small(const float* __restrict__ X, const float* __restrict__ W,
                  const float* __restrict__ S, const float* __restrict__ Bi,
                  float* __restrict__ O)
{
    const int n = (int)blockIdx.x;
    const int m = (int)threadIdx.x;
    float s = 0.f;
    for (int k = 0; k < K; ++k)
        s += (float)(_Float16)X[(size_t)m * K + k] * (float)(_Float16)W[(size_t)n * K + k];
    O[(size_t)m * N + n] = (float)(_Float16)((float)(_Float16)(s * S[n]) + Bi[n]);
}

extern "C" void kernel_launch(void* const* d_in, const int* in_sizes, int n_in,
                              void* d_out, int out_size, void* d_ws, size_t ws_size,
                              hipStream_t stream) {
    const float* x  = (const float*)d_in[0];
    const float* w  = (const float*)d_in[1];
    const float* s  = (const float*)d_in[2];
    const float* bi = (const float*)d_in[3];
    float* o = (float*)d_out;

    const size_t pbytes = (size_t)SPL * M * N * 2;   // 16 MB fp16 partials
    _Float16* P = (_Float16*)d_ws;

    if (ws_size >= pbytes) {
        gemm<<<dim3(512), dim3(256), 0, stream>>>(x, w, P);
        finalize<<<dim3(M * N / 8 / 256), dim3(256), 0, stream>>>(P, s, bi, o);
    } else {
        fp6lin_small<<<dim3(N), dim3(M), 0, stream>>>(x, w, s, bi, o);
    }
}